// Round 12
// baseline (416.539 us; speedup 1.0000x reference)
//
#include <hip/hip_runtime.h>

#define B_ROWS 65536
#define F_FEAT 39
#define V_VOC  100000
#define HALF_V 50000
#define D_PAD  640
#define BN_EPS 1e-5f

typedef __bf16 bf16x8 __attribute__((ext_vector_type(8)));
typedef float  f32x16 __attribute__((ext_vector_type(16)));
typedef unsigned int u32x4 __attribute__((ext_vector_type(4)));

__device__ __forceinline__ unsigned short toBF(float x) {
  unsigned int u = __float_as_uint(x);
  u += 0x7fffu + ((u >> 16) & 1u);
  return (unsigned short)(u >> 16);
}
__device__ __forceinline__ unsigned int pk2(float a, float b) {
  return (unsigned int)toBF(a) | ((unsigned int)toBF(b) << 16);
}

// ---------------- K0: transpose Xi/Xv to f-major; zero M; fill XT pad rows 624..639 ----------
__global__ __launch_bounds__(256) void k0_prep(
    const int* __restrict__ Xi, const float* __restrict__ Xv,
    int* __restrict__ XiT, float* __restrict__ XvT,
    float* __restrict__ M, unsigned short* __restrict__ XT) {
  for (int i = threadIdx.x; i < 800; i += 256)
    M[(size_t)blockIdx.x * 800 + i] = 0.f;

  const int b0 = blockIdx.x * 128;
  for (int u = threadIdx.x; u < 16 * 128; u += 256) {
    int m = 624 + (u >> 7), j = u & 127;
    XT[(size_t)m * B_ROWS + b0 + j] = (m == 624) ? (unsigned short)0x3f80 : (unsigned short)0;
  }

  __shared__ int   ti[128][41];
  __shared__ float tv[128][41];
  for (int u = threadIdx.x; u < 128 * 39; u += 256) {
    int r = u / 39, f = u - r * 39;
    ti[r][f] = Xi[(size_t)b0 * 39 + u];
    tv[r][f] = Xv[(size_t)b0 * 39 + u];
  }
  __syncthreads();
  for (int u = threadIdx.x; u < 39 * 128; u += 256) {
    int f = u >> 7, j = u & 127;
    XiT[(size_t)f * B_ROWS + b0 + j] = ti[j][f];
    XvT[(size_t)f * B_ROWS + b0 + j] = tv[j][f];
  }
}

// ---------------- K1s: L2-slice-pinned gather ------------------------------------------------
// 256 persistent blocks x 1024 threads. xcd = bid&7 (assumed round-robin dispatch; perf-only).
// Slices s = f*2+half (78 total); XCD x owns a contiguous run so both halves of an f run
// back-to-back on the same L2. Per slice: (P) stream the 3.2MB emb2 half-slice + 200KB emb1
// slice into L2 (coalesced, full BW); (G) masked gather - id in-range lanes read 64B rows
// that are now L2-resident. XB written with nontemporal stores to avoid evicting the slice.
__global__ __launch_bounds__(1024) void k1s_gather(
    const int* __restrict__ XiT, const float* __restrict__ XvT,
    const float* __restrict__ emb1, const float* __restrict__ emb2,
    unsigned short* __restrict__ XB, float* __restrict__ FS1) {
  const int xcd = blockIdx.x & 7;
  const int sub = blockIdx.x >> 3;          // 0..31: b-range owner within the XCD
  const int tid = threadIdx.x;
  const int sBeg = (xcd < 6) ? xcd * 10 : 60 + (xcd - 6) * 9;
  const int sEnd = sBeg + ((xcd < 6) ? 10 : 9);

  for (int s = sBeg; s < sEnd; ++s) {
    const int f = s >> 1;
    const unsigned vlo = (unsigned)(s & 1) * HALF_V;

    // ---- P: prefetch half-slice into this XCD's L2 ----
    const float4* p2 = reinterpret_cast<const float4*>(emb2 + ((size_t)f * V_VOC + vlo) * 16);
    const float4* p1 = reinterpret_cast<const float4*>(emb1 + (size_t)f * V_VOC + vlo);
    float sink = 0.f;
    const int tpos = sub * 1024 + tid;       // 0..32767 within XCD
#pragma unroll
    for (int i = 0; i < 7; ++i) {
      const int o = tpos + i * 32768;        // covers 200000 float4s
      if (o < HALF_V * 4) {
        float4 q = p2[o];
        sink += q.x + q.y + q.z + q.w;
      }
    }
    if (tpos < HALF_V / 4) {
      float4 q = p1[tpos];
      sink += q.x + q.y + q.z + q.w;
    }
    asm volatile("" :: "v"(sink));           // keep prefetch loads live (rule: no DCE)

    // ---- G: masked gather over this block's b-range ----
    const float* ef  = emb2 + (size_t)f * V_VOC * 16;
    const float* e1f = emb1 + (size_t)f * V_VOC;
    const size_t fb = (size_t)f * B_ROWS;
#pragma unroll
    for (int it = 0; it < 2; ++it) {
      const int b = sub * 2048 + it * 1024 + tid;
      const unsigned id = (unsigned)XiT[fb + b];
      if (id - vlo < (unsigned)HALF_V) {
        const float xv = XvT[fb + b];
        const float4* er = reinterpret_cast<const float4*>(ef + (size_t)id * 16);
        float4 q0 = er[0], q1 = er[1], q2 = er[2], q3 = er[3];
        u32x4 d0, d1;
        d0.x = pk2(q0.x * xv, q0.y * xv); d0.y = pk2(q0.z * xv, q0.w * xv);
        d0.z = pk2(q1.x * xv, q1.y * xv); d0.w = pk2(q1.z * xv, q1.w * xv);
        d1.x = pk2(q2.x * xv, q2.y * xv); d1.y = pk2(q2.z * xv, q2.w * xv);
        d1.z = pk2(q3.x * xv, q3.y * xv); d1.w = pk2(q3.z * xv, q3.w * xv);
        u32x4* dp = reinterpret_cast<u32x4*>(XB + (fb + b) * 16);
        __builtin_nontemporal_store(d0, dp);
        __builtin_nontemporal_store(d1, dp + 1);
        FS1[fb + b] = e1f[id] * xv;          // cached: small, merged in L2
      }
    }
  }
}

// ---------------- K_transpose: XB[f][b][16] -> XT[f*16+d][b] ----------------------------------
__global__ __launch_bounds__(256) void k_transpose(const unsigned short* __restrict__ XB,
                                                   unsigned short* __restrict__ XT) {
  const int f = blockIdx.y;
  const int b0 = blockIdx.x * 512;
  __shared__ unsigned int ls[16][257];
  const int t = threadIdx.x;
  const int bb = b0 + 2 * t;
  const uint4* s0 = reinterpret_cast<const uint4*>(XB + ((size_t)f * B_ROWS + bb) * 16);
  uint4 qa0 = s0[0], qa1 = s0[1], qb0 = s0[2], qb1 = s0[3];
  const unsigned short* pa0 = reinterpret_cast<const unsigned short*>(&qa0);
  const unsigned short* pa1 = reinterpret_cast<const unsigned short*>(&qa1);
  const unsigned short* pb0 = reinterpret_cast<const unsigned short*>(&qb0);
  const unsigned short* pb1 = reinterpret_cast<const unsigned short*>(&qb1);
#pragma unroll
  for (int d = 0; d < 8; ++d) {
    ls[d][t]     = (unsigned)pa0[d] | ((unsigned)pb0[d] << 16);
    ls[d + 8][t] = (unsigned)pa1[d] | ((unsigned)pb1[d] << 16);
  }
  __syncthreads();
#pragma unroll
  for (int d = 0; d < 16; ++d) {
    unsigned int* row = reinterpret_cast<unsigned int*>(
        XT + (size_t)(f * 16 + d) * B_ROWS + b0);
    row[t] = ls[d][t];
  }
}

// ---------------- K2: M += Xt * Xt^T  (640x640, symmetric tiles ti<=tj), bf16 MFMA ----------
#define KSPLIT 32
__global__ __launch_bounds__(256) void k2_syrk(const unsigned short* __restrict__ XT,
                                               float* __restrict__ M) {
  const int p = blockIdx.x;
  const int xcd = p & 7;
  const int ks = ((p >> 3) / 15) * 8 + xcd;   // 0..31
  int pair = (p >> 3) % 15;
  int ti = 0;
  while (pair >= 5 - ti) { pair -= 5 - ti; ++ti; }
  const int tj = ti + pair;

  __shared__ unsigned short pa[128 * 64];
  __shared__ unsigned short pb[128 * 64];

  const int lane = threadIdx.x & 63, wid = threadIdx.x >> 6;
  const int wm = wid >> 1, wn = wid & 1;
  const int rl = lane & 31, hh = lane >> 5;

  f32x16 acc00, acc01, acc10, acc11;
#pragma unroll
  for (int i = 0; i < 16; ++i) { acc00[i] = 0.f; acc01[i] = 0.f; acc10[i] = 0.f; acc11[i] = 0.f; }

  const int krange = B_ROWS / KSPLIT;  // 2048
  const int kbase = ks * krange;

  for (int kt = 0; kt < krange; kt += 64) {
    const int k0 = kbase + kt;
#pragma unroll
    for (int g2 = 0; g2 < 4; ++g2) {
      const int g = threadIdx.x + g2 * 256;
      const int r = g >> 3, j = g & 7;
      uint4 va = *reinterpret_cast<const uint4*>(XT + (size_t)(ti * 128 + r) * B_ROWS + k0 + j * 8);
      *reinterpret_cast<uint4*>((char*)pa + r * 128 + ((j ^ (r & 7)) << 4)) = va;
      uint4 vb = *reinterpret_cast<const uint4*>(XT + (size_t)(tj * 128 + r) * B_ROWS + k0 + j * 8);
      *reinterpret_cast<uint4*>((char*)pb + r * 128 + ((j ^ (r & 7)) << 4)) = vb;
    }
    __syncthreads();
#pragma unroll
    for (int kc = 0; kc < 4; ++kc) {
      const int ra0 = wm * 64 + rl, ra1 = wm * 64 + 32 + rl;
      const int rb0 = wn * 64 + rl, rb1 = wn * 64 + 32 + rl;
      bf16x8 a0 = *reinterpret_cast<const bf16x8*>((char*)pa + ra0 * 128 + (((kc * 2 + hh) ^ (ra0 & 7)) << 4));
      bf16x8 a1 = *reinterpret_cast<const bf16x8*>((char*)pa + ra1 * 128 + (((kc * 2 + hh) ^ (ra1 & 7)) << 4));
      bf16x8 b0 = *reinterpret_cast<const bf16x8*>((char*)pb + rb0 * 128 + (((kc * 2 + hh) ^ (rb0 & 7)) << 4));
      bf16x8 b1 = *reinterpret_cast<const bf16x8*>((char*)pb + rb1 * 128 + (((kc * 2 + hh) ^ (rb1 & 7)) << 4));
      acc00 = __builtin_amdgcn_mfma_f32_32x32x16_bf16(a0, b0, acc00, 0, 0, 0);
      acc01 = __builtin_amdgcn_mfma_f32_32x32x16_bf16(a0, b1, acc01, 0, 0, 0);
      acc10 = __builtin_amdgcn_mfma_f32_32x32x16_bf16(a1, b0, acc10, 0, 0, 0);
      acc11 = __builtin_amdgcn_mfma_f32_32x32x16_bf16(a1, b1, acc11, 0, 0, 0);
    }
    __syncthreads();
  }

#pragma unroll
  for (int rr = 0; rr < 16; ++rr) {
    const int rloc = (rr & 3) + ((rr >> 2) << 3) + hh * 4;
    const int row0 = ti * 128 + wm * 64 + rloc;
    const int row1 = row0 + 32;
    const int col0 = tj * 128 + wn * 64 + rl;
    atomicAdd(&M[row0 * D_PAD + col0], acc00[rr]);
    atomicAdd(&M[row0 * D_PAD + col0 + 32], acc01[rr]);
    atomicAdd(&M[row1 * D_PAD + col0], acc10[rr]);
    atomicAdd(&M[row1 * D_PAD + col0 + 32], acc11[rr]);
  }
}

// ---------------- K3a: Cov + mu from M --------------------------------------------------------
__device__ __forceinline__ float fetchM(const float* M, int a, int b) {
  if ((a >> 7) > (b >> 7)) { int t = a; a = b; b = t; }
  return M[a * D_PAD + b];
}
__global__ void k3a_cov(const float* __restrict__ M, float* __restrict__ Cov,
                        float* __restrict__ mu) {
  const int i = blockIdx.x;
  const float inv = 1.f / 65536.f;
  const float mui = fetchM(M, 624, i) * inv;
  for (int j = threadIdx.x; j < D_PAD; j += 256) {
    float muj = fetchM(M, 624, j) * inv;
    Cov[i * D_PAD + j] = fetchM(M, i, j) * inv - mui * muj;
    if (i == 0) mu[j] = muj;
  }
}

// ---------------- qform: alpha[k] = g[k] * rsqrt( W[:,k]^T Cov W[:,k] + eps ), 2 k's/block -----
__global__ __launch_bounds__(256) void qform(const float* __restrict__ Cov,
                                             const float* __restrict__ W, const int ldw,
                                             const float* __restrict__ g,
                                             float* __restrict__ alpha) {
  const int k0 = blockIdx.x * 2;
  __shared__ float w0s[624], w1s[624];
  for (int i = threadIdx.x; i < 624; i += 256) {
    w0s[i] = W[(size_t)i * ldw + k0];
    w1s[i] = W[(size_t)i * ldw + k0 + 1];
  }
  __syncthreads();
  const int j0 = threadIdx.x, j1 = threadIdx.x + 256, j2 = threadIdx.x + 512;
  const bool v2 = (j2 < 624);
  const float wj00 = w0s[j0], wj01 = w0s[j1], wj02 = v2 ? w0s[j2] : 0.f;
  const float wj10 = w1s[j0], wj11 = w1s[j1], wj12 = v2 ? w1s[j2] : 0.f;
  float acc0 = 0.f, acc1 = 0.f;
  for (int i = 0; i < 624; ++i) {
    const float wi0 = w0s[i], wi1 = w1s[i];
    const float* row = Cov + i * D_PAD;
    const float c0 = row[j0], c1 = row[j1], c2 = v2 ? row[j2] : 0.f;
    acc0 += wi0 * (c0 * wj00 + c1 * wj01 + c2 * wj02);
    acc1 += wi1 * (c0 * wj10 + c1 * wj11 + c2 * wj12);
  }
#pragma unroll
  for (int off = 32; off > 0; off >>= 1) {
    acc0 += __shfl_down(acc0, off);
    acc1 += __shfl_down(acc1, off);
  }
  __shared__ float pr[2][4];
  const int lane = threadIdx.x & 63, wv = threadIdx.x >> 6;
  if (lane == 0) { pr[0][wv] = acc0; pr[1][wv] = acc1; }
  __syncthreads();
  if (threadIdx.x == 0) {
    float v0 = pr[0][0] + pr[0][1] + pr[0][2] + pr[0][3];
    float v1 = pr[1][0] + pr[1][1] + pr[1][2] + pr[1][3];
    alpha[k0]     = g[k0]     * rsqrtf(v0 + BN_EPS);
    alpha[k0 + 1] = g[k0 + 1] * rsqrtf(v1 + BN_EPS);
  }
}

// ---------------- K3c: G[i][j] = sum_k W1[i][k]*alpha1[k]*W2[k][j] ----------------------------
__global__ __launch_bounds__(256) void k3c_G(const float* __restrict__ W1,
                                             const float* __restrict__ alpha1,
                                             const float* __restrict__ W2,
                                             float* __restrict__ G) {
  const int i = blockIdx.x;
  __shared__ float a[512];
  for (int k = threadIdx.x; k < 512; k += 256)
    a[k] = W1[(size_t)i * 512 + k] * alpha1[k];
  __syncthreads();
  const int j = threadIdx.x;
  float acc = 0.f;
#pragma unroll 8
  for (int k = 0; k < 512; ++k) acc += a[k] * W2[(size_t)k * 256 + j];
  G[(size_t)i * 256 + j] = acc;
}

// ---------------- K3e: gw[i] = sum_j G[i][j]*alpha2[j];  consts = bias + sum(be2) - mu.gw -----
__global__ __launch_bounds__(256) void k3e_final(const float* __restrict__ G,
                                                 const float* __restrict__ alpha2,
                                                 const float* __restrict__ mu,
                                                 const float* __restrict__ be2,
                                                 const float* __restrict__ bias,
                                                 float* __restrict__ gw,
                                                 float* __restrict__ consts) {
  __shared__ float a2[256];
  __shared__ float gws[640];
  a2[threadIdx.x] = alpha2[threadIdx.x];
  __syncthreads();
  for (int i = threadIdx.x; i < 640; i += 256) {
    float acc = 0.f;
    if (i < 624) {
      const float* gr = G + (size_t)i * 256;
#pragma unroll 8
      for (int j = 0; j < 256; ++j) acc += gr[j] * a2[j];
    }
    gw[i] = acc;
    gws[i] = acc;
  }
  __syncthreads();
  float pm = 0.f;
  for (int i = threadIdx.x; i < 624; i += 256) pm += mu[i] * gws[i];
  float val = be2[threadIdx.x] - pm;
#pragma unroll
  for (int off = 32; off > 0; off >>= 1) val += __shfl_down(val, off);
  __shared__ float pr[4];
  const int lane = threadIdx.x & 63, wv = threadIdx.x >> 6;
  if (lane == 0) pr[wv] = val;
  __syncthreads();
  if (threadIdx.x == 0) consts[0] = bias[0] + pr[0] + pr[1] + pr[2] + pr[3];
}

// ---------------- K5: out[b] = consts + sum_f FS1[f][b] + gw.x + 0.5*(|sum|^2 - ssq) ---------
__global__ __launch_bounds__(256) void k5_out(const float* __restrict__ FS1,
                                              const unsigned short* __restrict__ XT,
                                              const float* __restrict__ gw,
                                              const float* __restrict__ consts,
                                              float* __restrict__ out) {
  __shared__ float g[624];
  for (int m = threadIdx.x; m < 624; m += 256) g[m] = gw[m];
  __syncthreads();
  const int r = threadIdx.x >> 1, h = threadIdx.x & 1;
  const int b = blockIdx.x * 128 + r;
  const unsigned short* col = XT + b;

  float lin = 0.f, ssq = 0.f;
  float ps[16];
#pragma unroll
  for (int e = 0; e < 16; ++e) ps[e] = 0.f;

  const int m0 = h ? 320 : 0, m1 = h ? 624 : 320;
  for (int mo = m0; mo < m1; mo += 16) {
#pragma unroll
    for (int e = 0; e < 16; ++e) {
      const int m = mo + e;
      float x = __uint_as_float((unsigned int)col[(size_t)m * B_ROWS] << 16);
      lin += g[m] * x;
      ssq += x * x;
      ps[e] += x;
    }
  }
  const int fb = h ? 20 : 0, fe = h ? 39 : 20;
  for (int f = fb; f < fe; ++f)
    lin += FS1[(size_t)f * B_ROWS + b];

  float s2 = 0.f;
#pragma unroll
  for (int e = 0; e < 16; ++e) {
    float t = ps[e] + __shfl_xor(ps[e], 1);
    s2 += t * t;
  }
  // s2 is pair-total (identical on both lanes); lin/ssq are per-half partials.
  float tot = lin + 0.5f * (0.5f * s2 - ssq);
  tot += __shfl_xor(tot, 1);
  if (h == 0) out[b] = tot + consts[0];
}

// ---------------- host launch ----------------------------------------------------------------
extern "C" void kernel_launch(void* const* d_in, const int* in_sizes, int n_in,
                              void* d_out, int out_size, void* d_ws, size_t ws_size,
                              hipStream_t stream) {
  const int*   Xi   = (const int*)d_in[0];
  const float* Xv   = (const float*)d_in[1];
  const float* emb1 = (const float*)d_in[2];
  const float* emb2 = (const float*)d_in[3];
  const float* W1   = (const float*)d_in[4];
  const float* g1   = (const float*)d_in[6];
  const float* W2   = (const float*)d_in[8];
  const float* g2   = (const float*)d_in[10];
  const float* be2  = (const float*)d_in[11];
  const float* bias = (const float*)d_in[12];
  float* out = (float*)d_out;
  char* ws = (char*)d_ws;

  const size_t SZ_XT  = (size_t)D_PAD * B_ROWS * 2;          // 83.9 MB
  const size_t SZ_XB  = (size_t)F_FEAT * B_ROWS * 32;        // 81.8 MB
  const size_t SZ_FB  = (size_t)F_FEAT * B_ROWS * 4;         // 10.2 MB

  size_t off = 0;
  unsigned short* XT = (unsigned short*)(ws + off); off += SZ_XT;
  unsigned short* XB = (unsigned short*)(ws + off); off += SZ_XB;
  float* M    = (float*)(ws + off); off += (size_t)D_PAD * D_PAD * 4;
  float* COV  = (float*)(ws + off); off += (size_t)D_PAD * D_PAD * 4;
  float* MU   = (float*)(ws + off); off += D_PAD * 4;
  float* A1   = (float*)(ws + off); off += 512 * 4;
  float* A2   = (float*)(ws + off); off += 256 * 4;
  float* G    = (float*)(ws + off); off += (size_t)624 * 256 * 4;
  float* GW   = (float*)(ws + off); off += D_PAD * 4;
  float* CN   = (float*)(ws + off); off += 256;
  int*   XIT  = (int*)(ws + off);   off += SZ_FB;
  float* XVT  = (float*)(ws + off); off += SZ_FB;
  float* FS1  = (float*)(ws + off); off += SZ_FB;
  // total ~200 MB

  k0_prep<<<512, 256, 0, stream>>>(Xi, Xv, XIT, XVT, M, XT);
  k1s_gather<<<256, 1024, 0, stream>>>(XIT, XVT, emb1, emb2, XB, FS1);
  k_transpose<<<dim3(128, F_FEAT), 256, 0, stream>>>(XB, XT);
  k2_syrk<<<15 * KSPLIT, 256, 0, stream>>>(XT, M);
  k3a_cov<<<D_PAD, 256, 0, stream>>>(M, COV, MU);
  qform<<<256, 256, 0, stream>>>(COV, W1, 512, g1, A1);
  k3c_G<<<624, 256, 0, stream>>>(W1, A1, W2, G);
  qform<<<128, 256, 0, stream>>>(COV, G, 256, g2, A2);
  k3e_final<<<1, 256, 0, stream>>>(G, A2, MU, be2, bias, GW, CN);
  k5_out<<<512, 256, 0, stream>>>(FS1, XT, GW, CN, out);
}

// Round 13
// 353.359 us; speedup vs baseline: 1.1788x; 1.1788x over previous
//
#include <hip/hip_runtime.h>

#define B_ROWS 65536
#define F_FEAT 39
#define V_VOC  100000
#define D_PAD  640
#define BN_EPS 1e-5f
#define NPAIR  (39 * 32)

typedef __bf16 bf16x8 __attribute__((ext_vector_type(8)));
typedef float  f32x16 __attribute__((ext_vector_type(16)));

__device__ __forceinline__ unsigned short toBF(float x) {
  unsigned int u = __float_as_uint(x);
  u += 0x7fffu + ((u >> 16) & 1u);
  return (unsigned short)(u >> 16);
}

// ---------------- K0: transpose Xi/Xv to f-major; zero M; fill XT pad rows 624..639 ----------
__global__ __launch_bounds__(256) void k0_prep(
    const int* __restrict__ Xi, const float* __restrict__ Xv,
    int* __restrict__ XiT, float* __restrict__ XvT,
    float* __restrict__ M, unsigned short* __restrict__ XT) {
  for (int i = threadIdx.x; i < 800; i += 256)
    M[(size_t)blockIdx.x * 800 + i] = 0.f;

  const int b0 = blockIdx.x * 128;
  for (int u = threadIdx.x; u < 16 * 128; u += 256) {
    int m = 624 + (u >> 7), j = u & 127;
    XT[(size_t)m * B_ROWS + b0 + j] = (m == 624) ? (unsigned short)0x3f80 : (unsigned short)0;
  }

  __shared__ int   ti[128][41];
  __shared__ float tv[128][41];
  for (int u = threadIdx.x; u < 128 * 39; u += 256) {
    int r = u / 39, f = u - r * 39;
    ti[r][f] = Xi[(size_t)b0 * 39 + u];
    tv[r][f] = Xv[(size_t)b0 * 39 + u];
  }
  __syncthreads();
  for (int u = threadIdx.x; u < 39 * 128; u += 256) {
    int f = u >> 7, j = u & 127;
    XiT[(size_t)f * B_ROWS + b0 + j] = ti[j][f];
    XvT[(size_t)f * B_ROWS + b0 + j] = tv[j][f];
  }
}

// ---------------- K1f: persistent blocks, f-major work order (R7 structure, 2 blocks/CU) -----
__global__ __launch_bounds__(1024) void k1f_gather(
    const int* __restrict__ XiT, const float* __restrict__ XvT,
    const float* __restrict__ emb2, unsigned short* __restrict__ XT) {
  __shared__ unsigned short xs[2][16][264];

  const int seg = threadIdx.x & 3;        // 4-float segment of 16 dims
  const int bi  = threadIdx.x >> 2;       // 0..255: row within stripe
  const int dim = threadIdx.x >> 6;       // drain: 0..15
  const int prt = threadIdx.x & 63;       // drain: 64 x 8B per dim row

  for (int idx = blockIdx.x; idx < NPAIR; idx += gridDim.x) {
    const int f = idx >> 5;
    const int c = idx & 31;
    const int b0 = c * 2048;
    const float* ef = emb2 + (size_t)f * V_VOC * 16;
    const int*   xi = XiT + (size_t)f * B_ROWS + b0;
    const float* xv = XvT + (size_t)f * B_ROWS + b0;
    unsigned short* xtBase = XT + (size_t)(f * 16) * B_ROWS + b0;

    int   idA = xi[bi],        idB = xi[256 + bi];
    float xvA = xv[bi],        xvB = xv[256 + bi];
    float4 v = *reinterpret_cast<const float4*>(ef + (size_t)idA * 16 + seg * 4);

    for (int s = 0; s < 8; ++s) {
      const float4 cur = v;
      const float  xvc = xvA;
      idA = idB; xvA = xvB;
      if (s + 2 < 8) {
        idB = xi[(s + 2) * 256 + bi];
        xvB = xv[(s + 2) * 256 + bi];
      }
      if (s + 1 < 8)
        v = *reinterpret_cast<const float4*>(ef + (size_t)idA * 16 + seg * 4);

      const int bf = s & 1;
      xs[bf][seg * 4 + 0][bi] = toBF(cur.x * xvc);
      xs[bf][seg * 4 + 1][bi] = toBF(cur.y * xvc);
      xs[bf][seg * 4 + 2][bi] = toBF(cur.z * xvc);
      xs[bf][seg * 4 + 3][bi] = toBF(cur.w * xvc);
      __syncthreads();
      uint2 w = *reinterpret_cast<const uint2*>(&xs[bf][dim][prt * 4]);
      *reinterpret_cast<uint2*>(xtBase + (size_t)dim * B_ROWS + s * 256 + prt * 4) = w;
    }
    __syncthreads();
  }
}

// ---------------- K2: M += Xt * Xt^T  (640x640, symmetric tiles ti<=tj), bf16 MFMA ----------
#define KSPLIT 32
__global__ __launch_bounds__(256) void k2_syrk(const unsigned short* __restrict__ XT,
                                               float* __restrict__ M) {
  const int p = blockIdx.x;
  const int xcd = p & 7;
  const int ks = ((p >> 3) / 15) * 8 + xcd;   // 0..31
  int pair = (p >> 3) % 15;
  int ti = 0;
  while (pair >= 5 - ti) { pair -= 5 - ti; ++ti; }
  const int tj = ti + pair;

  __shared__ unsigned short pa[128 * 64];
  __shared__ unsigned short pb[128 * 64];

  const int lane = threadIdx.x & 63, wid = threadIdx.x >> 6;
  const int wm = wid >> 1, wn = wid & 1;
  const int rl = lane & 31, hh = lane >> 5;

  f32x16 acc00, acc01, acc10, acc11;
#pragma unroll
  for (int i = 0; i < 16; ++i) { acc00[i] = 0.f; acc01[i] = 0.f; acc10[i] = 0.f; acc11[i] = 0.f; }

  const int krange = B_ROWS / KSPLIT;  // 2048
  const int kbase = ks * krange;

  for (int kt = 0; kt < krange; kt += 64) {
    const int k0 = kbase + kt;
#pragma unroll
    for (int g2 = 0; g2 < 4; ++g2) {
      const int g = threadIdx.x + g2 * 256;
      const int r = g >> 3, j = g & 7;
      uint4 va = *reinterpret_cast<const uint4*>(XT + (size_t)(ti * 128 + r) * B_ROWS + k0 + j * 8);
      *reinterpret_cast<uint4*>((char*)pa + r * 128 + ((j ^ (r & 7)) << 4)) = va;
      uint4 vb = *reinterpret_cast<const uint4*>(XT + (size_t)(tj * 128 + r) * B_ROWS + k0 + j * 8);
      *reinterpret_cast<uint4*>((char*)pb + r * 128 + ((j ^ (r & 7)) << 4)) = vb;
    }
    __syncthreads();
#pragma unroll
    for (int kc = 0; kc < 4; ++kc) {
      const int ra0 = wm * 64 + rl, ra1 = wm * 64 + 32 + rl;
      const int rb0 = wn * 64 + rl, rb1 = wn * 64 + 32 + rl;
      bf16x8 a0 = *reinterpret_cast<const bf16x8*>((char*)pa + ra0 * 128 + (((kc * 2 + hh) ^ (ra0 & 7)) << 4));
      bf16x8 a1 = *reinterpret_cast<const bf16x8*>((char*)pa + ra1 * 128 + (((kc * 2 + hh) ^ (ra1 & 7)) << 4));
      bf16x8 b0 = *reinterpret_cast<const bf16x8*>((char*)pb + rb0 * 128 + (((kc * 2 + hh) ^ (rb0 & 7)) << 4));
      bf16x8 b1 = *reinterpret_cast<const bf16x8*>((char*)pb + rb1 * 128 + (((kc * 2 + hh) ^ (rb1 & 7)) << 4));
      acc00 = __builtin_amdgcn_mfma_f32_32x32x16_bf16(a0, b0, acc00, 0, 0, 0);
      acc01 = __builtin_amdgcn_mfma_f32_32x32x16_bf16(a0, b1, acc01, 0, 0, 0);
      acc10 = __builtin_amdgcn_mfma_f32_32x32x16_bf16(a1, b0, acc10, 0, 0, 0);
      acc11 = __builtin_amdgcn_mfma_f32_32x32x16_bf16(a1, b1, acc11, 0, 0, 0);
    }
    __syncthreads();
  }

#pragma unroll
  for (int rr = 0; rr < 16; ++rr) {
    const int rloc = (rr & 3) + ((rr >> 2) << 3) + hh * 4;
    const int row0 = ti * 128 + wm * 64 + rloc;
    const int row1 = row0 + 32;
    const int col0 = tj * 128 + wn * 64 + rl;
    atomicAdd(&M[row0 * D_PAD + col0], acc00[rr]);
    atomicAdd(&M[row0 * D_PAD + col0 + 32], acc01[rr]);
    atomicAdd(&M[row1 * D_PAD + col0], acc10[rr]);
    atomicAdd(&M[row1 * D_PAD + col0 + 32], acc11[rr]);
  }
}

// ---------------- K_mirror: fill lower-triangle tiles of M from upper ------------------------
__global__ __launch_bounds__(256) void k_mirror(float* __restrict__ M) {
  const int i = blockIdx.x;
  for (int j = threadIdx.x; j < D_PAD; j += 256)
    if ((i >> 7) > (j >> 7)) M[i * D_PAD + j] = M[j * D_PAD + i];
}

// ---------------- qform: alpha[k] = g[k]*rsqrt( (w^T M w)/N - (w.mu)^2 + eps ), 2 k/block ----
__global__ __launch_bounds__(256) void qform(const float* __restrict__ M,
                                             const float* __restrict__ W, const int ldw,
                                             const float* __restrict__ g,
                                             float* __restrict__ alpha) {
  const int k0 = blockIdx.x * 2;
  const float inv = 1.f / 65536.f;
  __shared__ float w0s[624], w1s[624];
  for (int i = threadIdx.x; i < 624; i += 256) {
    w0s[i] = W[(size_t)i * ldw + k0];
    w1s[i] = W[(size_t)i * ldw + k0 + 1];
  }
  __syncthreads();
  const int j0 = threadIdx.x, j1 = threadIdx.x + 256, j2 = threadIdx.x + 512;
  const bool v2 = (j2 < 624);
  const float wj00 = w0s[j0], wj01 = w0s[j1], wj02 = v2 ? w0s[j2] : 0.f;
  const float wj10 = w1s[j0], wj11 = w1s[j1], wj12 = v2 ? w1s[j2] : 0.f;
  // mu part: pm = w . mu (mu_j = M[624][j]*inv)
  const float* mrow = M + 624 * D_PAD;
  const float mu0 = mrow[j0] * inv, mu1 = mrow[j1] * inv, mu2 = v2 ? mrow[j2] * inv : 0.f;
  float pm0 = wj00 * mu0 + wj01 * mu1 + wj02 * mu2;
  float pm1 = wj10 * mu0 + wj11 * mu1 + wj12 * mu2;
  float acc0 = 0.f, acc1 = 0.f;
  for (int i = 0; i < 624; ++i) {
    const float wi0 = w0s[i], wi1 = w1s[i];
    const float* row = M + i * D_PAD;
    const float c0 = row[j0], c1 = row[j1], c2 = v2 ? row[j2] : 0.f;
    acc0 += wi0 * (c0 * wj00 + c1 * wj01 + c2 * wj02);
    acc1 += wi1 * (c0 * wj10 + c1 * wj11 + c2 * wj12);
  }
#pragma unroll
  for (int off = 32; off > 0; off >>= 1) {
    acc0 += __shfl_down(acc0, off);
    acc1 += __shfl_down(acc1, off);
    pm0  += __shfl_down(pm0, off);
    pm1  += __shfl_down(pm1, off);
  }
  __shared__ float pr[4][4];
  const int lane = threadIdx.x & 63, wv = threadIdx.x >> 6;
  if (lane == 0) { pr[0][wv] = acc0; pr[1][wv] = acc1; pr[2][wv] = pm0; pr[3][wv] = pm1; }
  __syncthreads();
  if (threadIdx.x == 0) {
    float a0 = pr[0][0] + pr[0][1] + pr[0][2] + pr[0][3];
    float a1 = pr[1][0] + pr[1][1] + pr[1][2] + pr[1][3];
    float p0 = pr[2][0] + pr[2][1] + pr[2][2] + pr[2][3];
    float p1 = pr[3][0] + pr[3][1] + pr[3][2] + pr[3][3];
    alpha[k0]     = g[k0]     * rsqrtf(a0 * inv - p0 * p0 + BN_EPS);
    alpha[k0 + 1] = g[k0 + 1] * rsqrtf(a1 * inv - p1 * p1 + BN_EPS);
  }
}

// ---------------- K3c: G[i][j] = sum_k W1[i][k]*alpha1[k]*W2[k][j] ----------------------------
__global__ __launch_bounds__(256) void k3c_G(const float* __restrict__ W1,
                                             const float* __restrict__ alpha1,
                                             const float* __restrict__ W2,
                                             float* __restrict__ G) {
  const int i = blockIdx.x;
  __shared__ float a[512];
  for (int k = threadIdx.x; k < 512; k += 256)
    a[k] = W1[(size_t)i * 512 + k] * alpha1[k];
  __syncthreads();
  const int j = threadIdx.x;
  float acc = 0.f;
#pragma unroll 8
  for (int k = 0; k < 512; ++k) acc += a[k] * W2[(size_t)k * 256 + j];
  G[(size_t)i * 256 + j] = acc;
}

// ---------------- K3e: gw[i] = sum_j G[i][j]*alpha2[j]; consts = bias + sum(be2) - mu.gw -----
__global__ __launch_bounds__(256) void k3e_final(const float* __restrict__ G,
                                                 const float* __restrict__ alpha2,
                                                 const float* __restrict__ M,
                                                 const float* __restrict__ be2,
                                                 const float* __restrict__ bias,
                                                 float* __restrict__ gw,
                                                 float* __restrict__ consts) {
  const float inv = 1.f / 65536.f;
  __shared__ float a2[256];
  __shared__ float gws[640];
  a2[threadIdx.x] = alpha2[threadIdx.x];
  __syncthreads();
  for (int i = threadIdx.x; i < 640; i += 256) {
    float acc = 0.f;
    if (i < 624) {
      const float* gr = G + (size_t)i * 256;
#pragma unroll 8
      for (int j = 0; j < 256; ++j) acc += gr[j] * a2[j];
    }
    gw[i] = acc;
    gws[i] = acc;
  }
  __syncthreads();
  float pm = 0.f;
  for (int i = threadIdx.x; i < 624; i += 256)
    pm += M[624 * D_PAD + i] * inv * gws[i];
  float val = be2[threadIdx.x] - pm;
#pragma unroll
  for (int off = 32; off > 0; off >>= 1) val += __shfl_down(val, off);
  __shared__ float pr[4];
  const int lane = threadIdx.x & 63, wv = threadIdx.x >> 6;
  if (lane == 0) pr[wv] = val;
  __syncthreads();
  if (threadIdx.x == 0) consts[0] = bias[0] + pr[0] + pr[1] + pr[2] + pr[3];
}

// ---------------- K5: out[b] = consts + first(emb1) + gw.x + 0.5*(|sum|^2 - ssq) -------------
__global__ __launch_bounds__(256) void k5_out(const int* __restrict__ Xi,
                                              const float* __restrict__ Xv,
                                              const float* __restrict__ emb1,
                                              const unsigned short* __restrict__ XT,
                                              const float* __restrict__ gw,
                                              const float* __restrict__ consts,
                                              float* __restrict__ out) {
  const int b0 = blockIdx.x * 128;
  __shared__ int   si[128][40];
  __shared__ float sx[128][40];
  __shared__ float g[624];
  for (int m = threadIdx.x; m < 624; m += 256) g[m] = gw[m];
  for (int u = threadIdx.x; u < 128 * 39; u += 256) {
    int rr = u / 39, ff = u - rr * 39;
    si[rr][ff] = Xi[(size_t)b0 * 39 + u];
    sx[rr][ff] = Xv[(size_t)b0 * 39 + u];
  }
  __syncthreads();
  const int r = threadIdx.x >> 1, h = threadIdx.x & 1;
  const int b = b0 + r;
  const unsigned short* col = XT + b;

  float lin = 0.f, ssq = 0.f;
  float ps[16];
#pragma unroll
  for (int e = 0; e < 16; ++e) ps[e] = 0.f;

  const int m0 = h ? 320 : 0, m1 = h ? 624 : 320;
  for (int mo = m0; mo < m1; mo += 16) {
#pragma unroll
    for (int e = 0; e < 16; ++e) {
      const int m = mo + e;
      float x = __uint_as_float((unsigned int)col[(size_t)m * B_ROWS] << 16);
      lin += g[m] * x;
      ssq += x * x;
      ps[e] += x;
    }
  }
  const int fb = h ? 20 : 0, fe = h ? 39 : 20;
  for (int f = fb; f < fe; ++f)
    lin += emb1[(size_t)f * V_VOC + si[r][f]] * sx[r][f];

  float s2 = 0.f;
#pragma unroll
  for (int e = 0; e < 16; ++e) {
    float t = ps[e] + __shfl_xor(ps[e], 1);
    s2 += t * t;
  }
  // s2 is pair-total (identical on both lanes); lin/ssq are per-half partials.
  float tot = lin + 0.5f * (0.5f * s2 - ssq);
  tot += __shfl_xor(tot, 1);
  if (h == 0) out[b] = tot + consts[0];
}

// ---------------- host launch ----------------------------------------------------------------
extern "C" void kernel_launch(void* const* d_in, const int* in_sizes, int n_in,
                              void* d_out, int out_size, void* d_ws, size_t ws_size,
                              hipStream_t stream) {
  const int*   Xi   = (const int*)d_in[0];
  const float* Xv   = (const float*)d_in[1];
  const float* emb1 = (const float*)d_in[2];
  const float* emb2 = (const float*)d_in[3];
  const float* W1   = (const float*)d_in[4];
  const float* g1   = (const float*)d_in[6];
  const float* W2   = (const float*)d_in[8];
  const float* g2   = (const float*)d_in[10];
  const float* be2  = (const float*)d_in[11];
  const float* bias = (const float*)d_in[12];
  float* out = (float*)d_out;
  char* ws = (char*)d_ws;

  const size_t SZ_XT = (size_t)D_PAD * B_ROWS * 2;           // 83.9 MB
  const size_t SZ_FB = (size_t)F_FEAT * B_ROWS * 4;          // 10.2 MB

  size_t off = 0;
  unsigned short* XT = (unsigned short*)(ws + off); off += SZ_XT;
  float* M   = (float*)(ws + off); off += (size_t)D_PAD * D_PAD * 4;
  float* A1  = (float*)(ws + off); off += 512 * 4;
  float* A2  = (float*)(ws + off); off += 256 * 4;
  float* G   = (float*)(ws + off); off += (size_t)624 * 256 * 4;
  float* GW  = (float*)(ws + off); off += D_PAD * 4;
  float* CN  = (float*)(ws + off); off += 256;
  int*   XIT = (int*)(ws + off);   off += SZ_FB;
  float* XVT = (float*)(ws + off); off += SZ_FB;
  // total ~107 MB

  k0_prep<<<512, 256, 0, stream>>>(Xi, Xv, XIT, XVT, M, XT);
  k1f_gather<<<512, 1024, 0, stream>>>(XIT, XVT, emb2, XT);
  k2_syrk<<<15 * KSPLIT, 256, 0, stream>>>(XT, M);
  k_mirror<<<D_PAD, 256, 0, stream>>>(M);
  qform<<<256, 256, 0, stream>>>(M, W1, 512, g1, A1);
  k3c_G<<<624, 256, 0, stream>>>(W1, A1, W2, G);
  qform<<<128, 256, 0, stream>>>(M, G, 256, g2, A2);
  k3e_final<<<1, 256, 0, stream>>>(G, A2, M, be2, bias, GW, CN);
  k5_out<<<512, 256, 0, stream>>>(Xi, Xv, emb1, XT, GW, CN, out);
}

// Round 14
// 351.478 us; speedup vs baseline: 1.1851x; 1.0054x over previous
//
#include <hip/hip_runtime.h>

#define B_ROWS 65536
#define F_FEAT 39
#define V_VOC  100000
#define D_PAD  640
#define BN_EPS 1e-5f
#define NPAIR  (39 * 32)

typedef __bf16 bf16x8 __attribute__((ext_vector_type(8)));
typedef float  f32x16 __attribute__((ext_vector_type(16)));

__device__ __forceinline__ unsigned short toBF(float x) {
  unsigned int u = __float_as_uint(x);
  u += 0x7fffu + ((u >> 16) & 1u);
  return (unsigned short)(u >> 16);
}

// ---------------- K0: transpose Xi/Xv to f-major; zero M; fill XT pad rows 624..639 ----------
__global__ __launch_bounds__(256) void k0_prep(
    const int* __restrict__ Xi, const float* __restrict__ Xv,
    int* __restrict__ XiT, float* __restrict__ XvT,
    float* __restrict__ M, unsigned short* __restrict__ XT) {
  for (int i = threadIdx.x; i < 800; i += 256)
    M[(size_t)blockIdx.x * 800 + i] = 0.f;

  const int b0 = blockIdx.x * 128;
  for (int u = threadIdx.x; u < 16 * 128; u += 256) {
    int m = 624 + (u >> 7), j = u & 127;
    XT[(size_t)m * B_ROWS + b0 + j] = (m == 624) ? (unsigned short)0x3f80 : (unsigned short)0;
  }

  __shared__ int   ti[128][41];
  __shared__ float tv[128][41];
  for (int u = threadIdx.x; u < 128 * 39; u += 256) {
    int r = u / 39, f = u - r * 39;
    ti[r][f] = Xi[(size_t)b0 * 39 + u];
    tv[r][f] = Xv[(size_t)b0 * 39 + u];
  }
  __syncthreads();
  for (int u = threadIdx.x; u < 39 * 128; u += 256) {
    int f = u >> 7, j = u & 127;
    XiT[(size_t)f * B_ROWS + b0 + j] = ti[j][f];
    XvT[(size_t)f * B_ROWS + b0 + j] = tv[j][f];
  }
}

// ---------------- K1f: persistent blocks, f-major work order (R7 launch: 256 x 1024) ---------
// One block per CU walks the f-major work queue in lockstep -> ~8-f active emb2 window.
// R13's 512-block variant (2/CU) broke lockstep: +16us. Grid must stay 256.
__global__ __launch_bounds__(1024) void k1f_gather(
    const int* __restrict__ XiT, const float* __restrict__ XvT,
    const float* __restrict__ emb2, unsigned short* __restrict__ XT) {
  __shared__ unsigned short xs[2][16][264];

  const int seg = threadIdx.x & 3;        // 4-float segment of 16 dims
  const int bi  = threadIdx.x >> 2;       // 0..255: row within stripe
  const int dim = threadIdx.x >> 6;       // drain: 0..15
  const int prt = threadIdx.x & 63;       // drain: 64 x 8B per dim row

  for (int idx = blockIdx.x; idx < NPAIR; idx += gridDim.x) {
    const int f = idx >> 5;
    const int c = idx & 31;
    const int b0 = c * 2048;
    const float* ef = emb2 + (size_t)f * V_VOC * 16;
    const int*   xi = XiT + (size_t)f * B_ROWS + b0;
    const float* xv = XvT + (size_t)f * B_ROWS + b0;
    unsigned short* xtBase = XT + (size_t)(f * 16) * B_ROWS + b0;

    int   idA = xi[bi],        idB = xi[256 + bi];
    float xvA = xv[bi],        xvB = xv[256 + bi];
    float4 v = *reinterpret_cast<const float4*>(ef + (size_t)idA * 16 + seg * 4);

    for (int s = 0; s < 8; ++s) {
      const float4 cur = v;
      const float  xvc = xvA;
      idA = idB; xvA = xvB;
      if (s + 2 < 8) {
        idB = xi[(s + 2) * 256 + bi];
        xvB = xv[(s + 2) * 256 + bi];
      }
      if (s + 1 < 8)
        v = *reinterpret_cast<const float4*>(ef + (size_t)idA * 16 + seg * 4);

      const int bf = s & 1;
      xs[bf][seg * 4 + 0][bi] = toBF(cur.x * xvc);
      xs[bf][seg * 4 + 1][bi] = toBF(cur.y * xvc);
      xs[bf][seg * 4 + 2][bi] = toBF(cur.z * xvc);
      xs[bf][seg * 4 + 3][bi] = toBF(cur.w * xvc);
      __syncthreads();
      uint2 w = *reinterpret_cast<const uint2*>(&xs[bf][dim][prt * 4]);
      *reinterpret_cast<uint2*>(xtBase + (size_t)dim * B_ROWS + s * 256 + prt * 4) = w;
    }
    __syncthreads();
  }
}

// ---------------- K2: M += Xt * Xt^T  (640x640, symmetric tiles ti<=tj), bf16 MFMA ----------
#define KSPLIT 32
__global__ __launch_bounds__(256) void k2_syrk(const unsigned short* __restrict__ XT,
                                               float* __restrict__ M) {
  const int p = blockIdx.x;
  const int xcd = p & 7;
  const int ks = ((p >> 3) / 15) * 8 + xcd;   // 0..31
  int pair = (p >> 3) % 15;
  int ti = 0;
  while (pair >= 5 - ti) { pair -= 5 - ti; ++ti; }
  const int tj = ti + pair;

  __shared__ unsigned short pa[128 * 64];
  __shared__ unsigned short pb[128 * 64];

  const int lane = threadIdx.x & 63, wid = threadIdx.x >> 6;
  const int wm = wid >> 1, wn = wid & 1;
  const int rl = lane & 31, hh = lane >> 5;

  f32x16 acc00, acc01, acc10, acc11;
#pragma unroll
  for (int i = 0; i < 16; ++i) { acc00[i] = 0.f; acc01[i] = 0.f; acc10[i] = 0.f; acc11[i] = 0.f; }

  const int krange = B_ROWS / KSPLIT;  // 2048
  const int kbase = ks * krange;

  for (int kt = 0; kt < krange; kt += 64) {
    const int k0 = kbase + kt;
#pragma unroll
    for (int g2 = 0; g2 < 4; ++g2) {
      const int g = threadIdx.x + g2 * 256;
      const int r = g >> 3, j = g & 7;
      uint4 va = *reinterpret_cast<const uint4*>(XT + (size_t)(ti * 128 + r) * B_ROWS + k0 + j * 8);
      *reinterpret_cast<uint4*>((char*)pa + r * 128 + ((j ^ (r & 7)) << 4)) = va;
      uint4 vb = *reinterpret_cast<const uint4*>(XT + (size_t)(tj * 128 + r) * B_ROWS + k0 + j * 8);
      *reinterpret_cast<uint4*>((char*)pb + r * 128 + ((j ^ (r & 7)) << 4)) = vb;
    }
    __syncthreads();
#pragma unroll
    for (int kc = 0; kc < 4; ++kc) {
      const int ra0 = wm * 64 + rl, ra1 = wm * 64 + 32 + rl;
      const int rb0 = wn * 64 + rl, rb1 = wn * 64 + 32 + rl;
      bf16x8 a0 = *reinterpret_cast<const bf16x8*>((char*)pa + ra0 * 128 + (((kc * 2 + hh) ^ (ra0 & 7)) << 4));
      bf16x8 a1 = *reinterpret_cast<const bf16x8*>((char*)pa + ra1 * 128 + (((kc * 2 + hh) ^ (ra1 & 7)) << 4));
      bf16x8 b0 = *reinterpret_cast<const bf16x8*>((char*)pb + rb0 * 128 + (((kc * 2 + hh) ^ (rb0 & 7)) << 4));
      bf16x8 b1 = *reinterpret_cast<const bf16x8*>((char*)pb + rb1 * 128 + (((kc * 2 + hh) ^ (rb1 & 7)) << 4));
      acc00 = __builtin_amdgcn_mfma_f32_32x32x16_bf16(a0, b0, acc00, 0, 0, 0);
      acc01 = __builtin_amdgcn_mfma_f32_32x32x16_bf16(a0, b1, acc01, 0, 0, 0);
      acc10 = __builtin_amdgcn_mfma_f32_32x32x16_bf16(a1, b0, acc10, 0, 0, 0);
      acc11 = __builtin_amdgcn_mfma_f32_32x32x16_bf16(a1, b1, acc11, 0, 0, 0);
    }
    __syncthreads();
  }

#pragma unroll
  for (int rr = 0; rr < 16; ++rr) {
    const int rloc = (rr & 3) + ((rr >> 2) << 3) + hh * 4;
    const int row0 = ti * 128 + wm * 64 + rloc;
    const int row1 = row0 + 32;
    const int col0 = tj * 128 + wn * 64 + rl;
    atomicAdd(&M[row0 * D_PAD + col0], acc00[rr]);
    atomicAdd(&M[row0 * D_PAD + col0 + 32], acc01[rr]);
    atomicAdd(&M[row1 * D_PAD + col0], acc10[rr]);
    atomicAdd(&M[row1 * D_PAD + col0 + 32], acc11[rr]);
  }
}

// ---------------- K_mirror: fill lower-triangle tiles of M from upper ------------------------
__global__ __launch_bounds__(256) void k_mirror(float* __restrict__ M) {
  const int i = blockIdx.x;
  for (int j = threadIdx.x; j < D_PAD; j += 256)
    if ((i >> 7) > (j >> 7)) M[i * D_PAD + j] = M[j * D_PAD + i];
}

// ---------------- qform: alpha[k] = g[k]*rsqrt( (w^T M w)/N - (w.mu)^2 + eps ), 2 k/block ----
__global__ __launch_bounds__(256) void qform(const float* __restrict__ M,
                                             const float* __restrict__ W, const int ldw,
                                             const float* __restrict__ g,
                                             float* __restrict__ alpha) {
  const int k0 = blockIdx.x * 2;
  const float inv = 1.f / 65536.f;
  __shared__ float w0s[624], w1s[624];
  for (int i = threadIdx.x; i < 624; i += 256) {
    w0s[i] = W[(size_t)i * ldw + k0];
    w1s[i] = W[(size_t)i * ldw + k0 + 1];
  }
  __syncthreads();
  const int j0 = threadIdx.x, j1 = threadIdx.x + 256, j2 = threadIdx.x + 512;
  const bool v2 = (j2 < 624);
  const float wj00 = w0s[j0], wj01 = w0s[j1], wj02 = v2 ? w0s[j2] : 0.f;
  const float wj10 = w1s[j0], wj11 = w1s[j1], wj12 = v2 ? w1s[j2] : 0.f;
  const float* mrow = M + 624 * D_PAD;
  const float mu0 = mrow[j0] * inv, mu1 = mrow[j1] * inv, mu2 = v2 ? mrow[j2] * inv : 0.f;
  float pm0 = wj00 * mu0 + wj01 * mu1 + wj02 * mu2;
  float pm1 = wj10 * mu0 + wj11 * mu1 + wj12 * mu2;
  float acc0 = 0.f, acc1 = 0.f;
  for (int i = 0; i < 624; ++i) {
    const float wi0 = w0s[i], wi1 = w1s[i];
    const float* row = M + i * D_PAD;
    const float c0 = row[j0], c1 = row[j1], c2 = v2 ? row[j2] : 0.f;
    acc0 += wi0 * (c0 * wj00 + c1 * wj01 + c2 * wj02);
    acc1 += wi1 * (c0 * wj10 + c1 * wj11 + c2 * wj12);
  }
#pragma unroll
  for (int off = 32; off > 0; off >>= 1) {
    acc0 += __shfl_down(acc0, off);
    acc1 += __shfl_down(acc1, off);
    pm0  += __shfl_down(pm0, off);
    pm1  += __shfl_down(pm1, off);
  }
  __shared__ float pr[4][4];
  const int lane = threadIdx.x & 63, wv = threadIdx.x >> 6;
  if (lane == 0) { pr[0][wv] = acc0; pr[1][wv] = acc1; pr[2][wv] = pm0; pr[3][wv] = pm1; }
  __syncthreads();
  if (threadIdx.x == 0) {
    float a0 = pr[0][0] + pr[0][1] + pr[0][2] + pr[0][3];
    float a1 = pr[1][0] + pr[1][1] + pr[1][2] + pr[1][3];
    float p0 = pr[2][0] + pr[2][1] + pr[2][2] + pr[2][3];
    float p1 = pr[3][0] + pr[3][1] + pr[3][2] + pr[3][3];
    alpha[k0]     = g[k0]     * rsqrtf(a0 * inv - p0 * p0 + BN_EPS);
    alpha[k0 + 1] = g[k0 + 1] * rsqrtf(a1 * inv - p1 * p1 + BN_EPS);
  }
}

// ---------------- K3c: G[i][j] = sum_k W1[i][k]*alpha1[k]*W2[k][j] ----------------------------
__global__ __launch_bounds__(256) void k3c_G(const float* __restrict__ W1,
                                             const float* __restrict__ alpha1,
                                             const float* __restrict__ W2,
                                             float* __restrict__ G) {
  const int i = blockIdx.x;
  __shared__ float a[512];
  for (int k = threadIdx.x; k < 512; k += 256)
    a[k] = W1[(size_t)i * 512 + k] * alpha1[k];
  __syncthreads();
  const int j = threadIdx.x;
  float acc = 0.f;
#pragma unroll 8
  for (int k = 0; k < 512; ++k) acc += a[k] * W2[(size_t)k * 256 + j];
  G[(size_t)i * 256 + j] = acc;
}

// ---------------- K3e: gw[i] = sum_j G[i][j]*alpha2[j]; consts = bias + sum(be2) - mu.gw -----
__global__ __launch_bounds__(256) void k3e_final(const float* __restrict__ G,
                                                 const float* __restrict__ alpha2,
                                                 const float* __restrict__ M,
                                                 const float* __restrict__ be2,
                                                 const float* __restrict__ bias,
                                                 float* __restrict__ gw,
                                                 float* __restrict__ consts) {
  const float inv = 1.f / 65536.f;
  __shared__ float a2[256];
  __shared__ float gws[640];
  a2[threadIdx.x] = alpha2[threadIdx.x];
  __syncthreads();
  for (int i = threadIdx.x; i < 640; i += 256) {
    float acc = 0.f;
    if (i < 624) {
      const float* gr = G + (size_t)i * 256;
#pragma unroll 8
      for (int j = 0; j < 256; ++j) acc += gr[j] * a2[j];
    }
    gw[i] = acc;
    gws[i] = acc;
  }
  __syncthreads();
  float pm = 0.f;
  for (int i = threadIdx.x; i < 624; i += 256)
    pm += M[624 * D_PAD + i] * inv * gws[i];
  float val = be2[threadIdx.x] - pm;
#pragma unroll
  for (int off = 32; off > 0; off >>= 1) val += __shfl_down(val, off);
  __shared__ float pr[4];
  const int lane = threadIdx.x & 63, wv = threadIdx.x >> 6;
  if (lane == 0) pr[wv] = val;
  __syncthreads();
  if (threadIdx.x == 0) consts[0] = bias[0] + pr[0] + pr[1] + pr[2] + pr[3];
}

// ---------------- K5: out[b] = consts + first(emb1) + gw.x + 0.5*(|sum|^2 - ssq) -------------
__global__ __launch_bounds__(256) void k5_out(const int* __restrict__ Xi,
                                              const float* __restrict__ Xv,
                                              const float* __restrict__ emb1,
                                              const unsigned short* __restrict__ XT,
                                              const float* __restrict__ gw,
                                              const float* __restrict__ consts,
                                              float* __restrict__ out) {
  const int b0 = blockIdx.x * 128;
  __shared__ int   si[128][40];
  __shared__ float sx[128][40];
  __shared__ float g[624];
  for (int m = threadIdx.x; m < 624; m += 256) g[m] = gw[m];
  for (int u = threadIdx.x; u < 128 * 39; u += 256) {
    int rr = u / 39, ff = u - rr * 39;
    si[rr][ff] = Xi[(size_t)b0 * 39 + u];
    sx[rr][ff] = Xv[(size_t)b0 * 39 + u];
  }
  __syncthreads();
  const int r = threadIdx.x >> 1, h = threadIdx.x & 1;
  const int b = b0 + r;
  const unsigned short* col = XT + b;

  float lin = 0.f, ssq = 0.f;
  float ps[16];
#pragma unroll
  for (int e = 0; e < 16; ++e) ps[e] = 0.f;

  const int m0 = h ? 320 : 0, m1 = h ? 624 : 320;
  for (int mo = m0; mo < m1; mo += 16) {
#pragma unroll
    for (int e = 0; e < 16; ++e) {
      const int m = mo + e;
      float x = __uint_as_float((unsigned int)col[(size_t)m * B_ROWS] << 16);
      lin += g[m] * x;
      ssq += x * x;
      ps[e] += x;
    }
  }
  const int fb = h ? 20 : 0, fe = h ? 39 : 20;
  for (int f = fb; f < fe; ++f)
    lin += emb1[(size_t)f * V_VOC + si[r][f]] * sx[r][f];

  float s2 = 0.f;
#pragma unroll
  for (int e = 0; e < 16; ++e) {
    float t = ps[e] + __shfl_xor(ps[e], 1);
    s2 += t * t;
  }
  // s2 is pair-total (identical on both lanes); lin/ssq are per-half partials.
  float tot = lin + 0.5f * (0.5f * s2 - ssq);
  tot += __shfl_xor(tot, 1);
  if (h == 0) out[b] = tot + consts[0];
}

// ---------------- host launch ----------------------------------------------------------------
extern "C" void kernel_launch(void* const* d_in, const int* in_sizes, int n_in,
                              void* d_out, int out_size, void* d_ws, size_t ws_size,
                              hipStream_t stream) {
  const int*   Xi   = (const int*)d_in[0];
  const float* Xv   = (const float*)d_in[1];
  const float* emb1 = (const float*)d_in[2];
  const float* emb2 = (const float*)d_in[3];
  const float* W1   = (const float*)d_in[4];
  const float* g1   = (const float*)d_in[6];
  const float* W2   = (const float*)d_in[8];
  const float* g2   = (const float*)d_in[10];
  const float* be2  = (const float*)d_in[11];
  const float* bias = (const float*)d_in[12];
  float* out = (float*)d_out;
  char* ws = (char*)d_ws;

  const size_t SZ_XT = (size_t)D_PAD * B_ROWS * 2;           // 83.9 MB
  const size_t SZ_FB = (size_t)F_FEAT * B_ROWS * 4;          // 10.2 MB

  size_t off = 0;
  unsigned short* XT = (unsigned short*)(ws + off); off += SZ_XT;
  float* M   = (float*)(ws + off); off += (size_t)D_PAD * D_PAD * 4;
  float* A1  = (float*)(ws + off); off += 512 * 4;
  float* A2  = (float*)(ws + off); off += 256 * 4;
  float* G   = (float*)(ws + off); off += (size_t)624 * 256 * 4;
  float* GW  = (float*)(ws + off); off += D_PAD * 4;
  float* CN  = (float*)(ws + off); off += 256;
  int*   XIT = (int*)(ws + off);   off += SZ_FB;
  float* XVT = (float*)(ws + off); off += SZ_FB;
  // total ~107 MB

  k0_prep<<<512, 256, 0, stream>>>(Xi, Xv, XIT, XVT, M, XT);
  k1f_gather<<<256, 1024, 0, stream>>>(XIT, XVT, emb2, XT);
  k2_syrk<<<15 * KSPLIT, 256, 0, stream>>>(XT, M);
  k_mirror<<<D_PAD, 256, 0, stream>>>(M);
  qform<<<256, 256, 0, stream>>>(M, W1, 512, g1, A1);
  k3c_G<<<624, 256, 0, stream>>>(W1, A1, W2, G);
  qform<<<128, 256, 0, stream>>>(M, G, 256, g2, A2);
  k3e_final<<<1, 256, 0, stream>>>(G, A2, M, be2, bias, GW, CN);
  k5_out<<<512, 256, 0, stream>>>(Xi, Xv, emb1, XT, GW, CN, out);
}

// Round 15
// 350.029 us; speedup vs baseline: 1.1900x; 1.0041x over previous
//
#include <hip/hip_runtime.h>

#define B_ROWS 65536
#define F_FEAT 39
#define V_VOC  100000
#define D_PAD  640
#define BN_EPS 1e-5f
#define NPAIR  (39 * 32)

typedef __bf16 bf16x8 __attribute__((ext_vector_type(8)));
typedef float  f32x16 __attribute__((ext_vector_type(16)));

__device__ __forceinline__ unsigned short toBF(float x) {
  unsigned int u = __float_as_uint(x);
  u += 0x7fffu + ((u >> 16) & 1u);
  return (unsigned short)(u >> 16);
}

// async global->LDS 16B copy (dest: wave-uniform base + lane*16; src: per-lane)
__device__ __forceinline__ void load_lds16(const void* gptr, void* lptr) {
  __builtin_amdgcn_global_load_lds(
      (const __attribute__((address_space(1))) void*)gptr,
      (__attribute__((address_space(3))) void*)lptr, 16, 0, 0);
}

// ---------------- K0: transpose Xi/Xv to f-major; zero M; fill XT pad rows 624..639 ----------
__global__ __launch_bounds__(256) void k0_prep(
    const int* __restrict__ Xi, const float* __restrict__ Xv,
    int* __restrict__ XiT, float* __restrict__ XvT,
    float* __restrict__ M, unsigned short* __restrict__ XT) {
  for (int i = threadIdx.x; i < 800; i += 256)
    M[(size_t)blockIdx.x * 800 + i] = 0.f;

  const int b0 = blockIdx.x * 128;
  for (int u = threadIdx.x; u < 16 * 128; u += 256) {
    int m = 624 + (u >> 7), j = u & 127;
    XT[(size_t)m * B_ROWS + b0 + j] = (m == 624) ? (unsigned short)0x3f80 : (unsigned short)0;
  }

  __shared__ int   ti[128][41];
  __shared__ float tv[128][41];
  for (int u = threadIdx.x; u < 128 * 39; u += 256) {
    int r = u / 39, f = u - r * 39;
    ti[r][f] = Xi[(size_t)b0 * 39 + u];
    tv[r][f] = Xv[(size_t)b0 * 39 + u];
  }
  __syncthreads();
  for (int u = threadIdx.x; u < 39 * 128; u += 256) {
    int f = u >> 7, j = u & 127;
    XiT[(size_t)f * B_ROWS + b0 + j] = ti[j][f];
    XvT[(size_t)f * B_ROWS + b0 + j] = tv[j][f];
  }
}

// ---------------- K1f: persistent blocks, f-major work order (256 x 1024, 1 block/CU) --------
__global__ __launch_bounds__(1024) void k1f_gather(
    const int* __restrict__ XiT, const float* __restrict__ XvT,
    const float* __restrict__ emb2, unsigned short* __restrict__ XT) {
  __shared__ unsigned short xs[2][16][264];

  const int seg = threadIdx.x & 3;
  const int bi  = threadIdx.x >> 2;
  const int dim = threadIdx.x >> 6;
  const int prt = threadIdx.x & 63;

  for (int idx = blockIdx.x; idx < NPAIR; idx += gridDim.x) {
    const int f = idx >> 5;
    const int c = idx & 31;
    const int b0 = c * 2048;
    const float* ef = emb2 + (size_t)f * V_VOC * 16;
    const int*   xi = XiT + (size_t)f * B_ROWS + b0;
    const float* xv = XvT + (size_t)f * B_ROWS + b0;
    unsigned short* xtBase = XT + (size_t)(f * 16) * B_ROWS + b0;

    int   idA = xi[bi],        idB = xi[256 + bi];
    float xvA = xv[bi],        xvB = xv[256 + bi];
    float4 v = *reinterpret_cast<const float4*>(ef + (size_t)idA * 16 + seg * 4);

    for (int s = 0; s < 8; ++s) {
      const float4 cur = v;
      const float  xvc = xvA;
      idA = idB; xvA = xvB;
      if (s + 2 < 8) {
        idB = xi[(s + 2) * 256 + bi];
        xvB = xv[(s + 2) * 256 + bi];
      }
      if (s + 1 < 8)
        v = *reinterpret_cast<const float4*>(ef + (size_t)idA * 16 + seg * 4);

      const int bf = s & 1;
      xs[bf][seg * 4 + 0][bi] = toBF(cur.x * xvc);
      xs[bf][seg * 4 + 1][bi] = toBF(cur.y * xvc);
      xs[bf][seg * 4 + 2][bi] = toBF(cur.z * xvc);
      xs[bf][seg * 4 + 3][bi] = toBF(cur.w * xvc);
      __syncthreads();
      uint2 w = *reinterpret_cast<const uint2*>(&xs[bf][dim][prt * 4]);
      *reinterpret_cast<uint2*>(xtBase + (size_t)dim * B_ROWS + s * 256 + prt * 4) = w;
    }
    __syncthreads();
  }
}

// ---------------- K2: M += Xt * Xt^T  (640x640, symmetric tiles ti<=tj), bf16 MFMA ----------
// Staging now via global_load_lds (16B, async, no VGPR round-trip). LDS layout is LINEAR in
// g (dest = pa + g*16 = wave-uniform base + lane*16); the bank-conflict XOR swizzle moved to
// the GLOBAL source column (j' = j^(r&7)) per rule "both-sides-or-neither". LDS contents are
// bit-identical to the old explicit-store version; ds_read side unchanged.
#define KSPLIT 32
__global__ __launch_bounds__(256) void k2_syrk(const unsigned short* __restrict__ XT,
                                               float* __restrict__ M) {
  const int p = blockIdx.x;
  const int xcd = p & 7;
  const int ks = ((p >> 3) / 15) * 8 + xcd;   // 0..31
  int pair = (p >> 3) % 15;
  int ti = 0;
  while (pair >= 5 - ti) { pair -= 5 - ti; ++ti; }
  const int tj = ti + pair;

  __shared__ unsigned short pa[128 * 64];
  __shared__ unsigned short pb[128 * 64];

  const int lane = threadIdx.x & 63, wid = threadIdx.x >> 6;
  const int wm = wid >> 1, wn = wid & 1;
  const int rl = lane & 31, hh = lane >> 5;

  f32x16 acc00, acc01, acc10, acc11;
#pragma unroll
  for (int i = 0; i < 16; ++i) { acc00[i] = 0.f; acc01[i] = 0.f; acc10[i] = 0.f; acc11[i] = 0.f; }

  const int krange = B_ROWS / KSPLIT;  // 2048
  const int kbase = ks * krange;

  for (int kt = 0; kt < krange; kt += 64) {
    const int k0 = kbase + kt;
#pragma unroll
    for (int g2 = 0; g2 < 4; ++g2) {
      const int g = threadIdx.x + g2 * 256;
      const int r = g >> 3, j = g & 7;
      const int js = j ^ (r & 7);
      load_lds16(XT + (size_t)(ti * 128 + r) * B_ROWS + k0 + js * 8, (char*)pa + g * 16);
      load_lds16(XT + (size_t)(tj * 128 + r) * B_ROWS + k0 + js * 8, (char*)pb + g * 16);
    }
    __syncthreads();
#pragma unroll
    for (int kc = 0; kc < 4; ++kc) {
      const int ra0 = wm * 64 + rl, ra1 = wm * 64 + 32 + rl;
      const int rb0 = wn * 64 + rl, rb1 = wn * 64 + 32 + rl;
      bf16x8 a0 = *reinterpret_cast<const bf16x8*>((char*)pa + ra0 * 128 + (((kc * 2 + hh) ^ (ra0 & 7)) << 4));
      bf16x8 a1 = *reinterpret_cast<const bf16x8*>((char*)pa + ra1 * 128 + (((kc * 2 + hh) ^ (ra1 & 7)) << 4));
      bf16x8 b0 = *reinterpret_cast<const bf16x8*>((char*)pb + rb0 * 128 + (((kc * 2 + hh) ^ (rb0 & 7)) << 4));
      bf16x8 b1 = *reinterpret_cast<const bf16x8*>((char*)pb + rb1 * 128 + (((kc * 2 + hh) ^ (rb1 & 7)) << 4));
      acc00 = __builtin_amdgcn_mfma_f32_32x32x16_bf16(a0, b0, acc00, 0, 0, 0);
      acc01 = __builtin_amdgcn_mfma_f32_32x32x16_bf16(a0, b1, acc01, 0, 0, 0);
      acc10 = __builtin_amdgcn_mfma_f32_32x32x16_bf16(a1, b0, acc10, 0, 0, 0);
      acc11 = __builtin_amdgcn_mfma_f32_32x32x16_bf16(a1, b1, acc11, 0, 0, 0);
    }
    __syncthreads();
  }

#pragma unroll
  for (int rr = 0; rr < 16; ++rr) {
    const int rloc = (rr & 3) + ((rr >> 2) << 3) + hh * 4;
    const int row0 = ti * 128 + wm * 64 + rloc;
    const int row1 = row0 + 32;
    const int col0 = tj * 128 + wn * 64 + rl;
    atomicAdd(&M[row0 * D_PAD + col0], acc00[rr]);
    atomicAdd(&M[row0 * D_PAD + col0 + 32], acc01[rr]);
    atomicAdd(&M[row1 * D_PAD + col0], acc10[rr]);
    atomicAdd(&M[row1 * D_PAD + col0 + 32], acc11[rr]);
  }
}

// ---------------- K_mirror: fill lower-triangle tiles of M from upper ------------------------
__global__ __launch_bounds__(256) void k_mirror(float* __restrict__ M) {
  const int i = blockIdx.x;
  for (int j = threadIdx.x; j < D_PAD; j += 256)
    if ((i >> 7) > (j >> 7)) M[i * D_PAD + j] = M[j * D_PAD + i];
}

// ---------------- qform: alpha[k] = g[k]*rsqrt( (w^T M w)/N - (w.mu)^2 + eps ), 2 k/block ----
__global__ __launch_bounds__(256) void qform(const float* __restrict__ M,
                                             const float* __restrict__ W, const int ldw,
                                             const float* __restrict__ g,
                                             float* __restrict__ alpha) {
  const int k0 = blockIdx.x * 2;
  const float inv = 1.f / 65536.f;
  __shared__ float w0s[624], w1s[624];
  for (int i = threadIdx.x; i < 624; i += 256) {
    w0s[i] = W[(size_t)i * ldw + k0];
    w1s[i] = W[(size_t)i * ldw + k0 + 1];
  }
  __syncthreads();
  const int j0 = threadIdx.x, j1 = threadIdx.x + 256, j2 = threadIdx.x + 512;
  const bool v2 = (j2 < 624);
  const float wj00 = w0s[j0], wj01 = w0s[j1], wj02 = v2 ? w0s[j2] : 0.f;
  const float wj10 = w1s[j0], wj11 = w1s[j1], wj12 = v2 ? w1s[j2] : 0.f;
  const float* mrow = M + 624 * D_PAD;
  const float mu0 = mrow[j0] * inv, mu1 = mrow[j1] * inv, mu2 = v2 ? mrow[j2] * inv : 0.f;
  float pm0 = wj00 * mu0 + wj01 * mu1 + wj02 * mu2;
  float pm1 = wj10 * mu0 + wj11 * mu1 + wj12 * mu2;
  float acc0 = 0.f, acc1 = 0.f;
  for (int i = 0; i < 624; ++i) {
    const float wi0 = w0s[i], wi1 = w1s[i];
    const float* row = M + i * D_PAD;
    const float c0 = row[j0], c1 = row[j1], c2 = v2 ? row[j2] : 0.f;
    acc0 += wi0 * (c0 * wj00 + c1 * wj01 + c2 * wj02);
    acc1 += wi1 * (c0 * wj10 + c1 * wj11 + c2 * wj12);
  }
#pragma unroll
  for (int off = 32; off > 0; off >>= 1) {
    acc0 += __shfl_down(acc0, off);
    acc1 += __shfl_down(acc1, off);
    pm0  += __shfl_down(pm0, off);
    pm1  += __shfl_down(pm1, off);
  }
  __shared__ float pr[4][4];
  const int lane = threadIdx.x & 63, wv = threadIdx.x >> 6;
  if (lane == 0) { pr[0][wv] = acc0; pr[1][wv] = acc1; pr[2][wv] = pm0; pr[3][wv] = pm1; }
  __syncthreads();
  if (threadIdx.x == 0) {
    float a0 = pr[0][0] + pr[0][1] + pr[0][2] + pr[0][3];
    float a1 = pr[1][0] + pr[1][1] + pr[1][2] + pr[1][3];
    float p0 = pr[2][0] + pr[2][1] + pr[2][2] + pr[2][3];
    float p1 = pr[3][0] + pr[3][1] + pr[3][2] + pr[3][3];
    alpha[k0]     = g[k0]     * rsqrtf(a0 * inv - p0 * p0 + BN_EPS);
    alpha[k0 + 1] = g[k0 + 1] * rsqrtf(a1 * inv - p1 * p1 + BN_EPS);
  }
}

// ---------------- K3c: G[i][j] = sum_k W1[i][k]*alpha1[k]*W2[k][j] ----------------------------
__global__ __launch_bounds__(256) void k3c_G(const float* __restrict__ W1,
                                             const float* __restrict__ alpha1,
                                             const float* __restrict__ W2,
                                             float* __restrict__ G) {
  const int i = blockIdx.x;
  __shared__ float a[512];
  for (int k = threadIdx.x; k < 512; k += 256)
    a[k] = W1[(size_t)i * 512 + k] * alpha1[k];
  __syncthreads();
  const int j = threadIdx.x;
  float acc = 0.f;
#pragma unroll 8
  for (int k = 0; k < 512; ++k) acc += a[k] * W2[(size_t)k * 256 + j];
  G[(size_t)i * 256 + j] = acc;
}

// ---------------- K3e: gw[i] = sum_j G[i][j]*alpha2[j]; consts = bias + sum(be2) - mu.gw -----
__global__ __launch_bounds__(256) void k3e_final(const float* __restrict__ G,
                                                 const float* __restrict__ alpha2,
                                                 const float* __restrict__ M,
                                                 const float* __restrict__ be2,
                                                 const float* __restrict__ bias,
                                                 float* __restrict__ gw,
                                                 float* __restrict__ consts) {
  const float inv = 1.f / 65536.f;
  __shared__ float a2[256];
  __shared__ float gws[640];
  a2[threadIdx.x] = alpha2[threadIdx.x];
  __syncthreads();
  for (int i = threadIdx.x; i < 640; i += 256) {
    float acc = 0.f;
    if (i < 624) {
      const float* gr = G + (size_t)i * 256;
#pragma unroll 8
      for (int j = 0; j < 256; ++j) acc += gr[j] * a2[j];
    }
    gw[i] = acc;
    gws[i] = acc;
  }
  __syncthreads();
  float pm = 0.f;
  for (int i = threadIdx.x; i < 624; i += 256)
    pm += M[624 * D_PAD + i] * inv * gws[i];
  float val = be2[threadIdx.x] - pm;
#pragma unroll
  for (int off = 32; off > 0; off >>= 1) val += __shfl_down(val, off);
  __shared__ float pr[4];
  const int lane = threadIdx.x & 63, wv = threadIdx.x >> 6;
  if (lane == 0) pr[wv] = val;
  __syncthreads();
  if (threadIdx.x == 0) consts[0] = bias[0] + pr[0] + pr[1] + pr[2] + pr[3];
}

// ---------------- K5: out[b] = consts + first(emb1) + gw.x + 0.5*(|sum|^2 - ssq) -------------
__global__ __launch_bounds__(256) void k5_out(const int* __restrict__ Xi,
                                              const float* __restrict__ Xv,
                                              const float* __restrict__ emb1,
                                              const unsigned short* __restrict__ XT,
                                              const float* __restrict__ gw,
                                              const float* __restrict__ consts,
                                              float* __restrict__ out) {
  const int b0 = blockIdx.x * 128;
  __shared__ int   si[128][40];
  __shared__ float sx[128][40];
  __shared__ float g[624];
  for (int m = threadIdx.x; m < 624; m += 256) g[m] = gw[m];
  for (int u = threadIdx.x; u < 128 * 39; u += 256) {
    int rr = u / 39, ff = u - rr * 39;
    si[rr][ff] = Xi[(size_t)b0 * 39 + u];
    sx[rr][ff] = Xv[(size_t)b0 * 39 + u];
  }
  __syncthreads();
  const int r = threadIdx.x >> 1, h = threadIdx.x & 1;
  const int b = b0 + r;
  const unsigned short* col = XT + b;

  float lin = 0.f, ssq = 0.f;
  float ps[16];
#pragma unroll
  for (int e = 0; e < 16; ++e) ps[e] = 0.f;

  const int m0 = h ? 320 : 0, m1 = h ? 624 : 320;
  for (int mo = m0; mo < m1; mo += 16) {
#pragma unroll
    for (int e = 0; e < 16; ++e) {
      const int m = mo + e;
      float x = __uint_as_float((unsigned int)col[(size_t)m * B_ROWS] << 16);
      lin += g[m] * x;
      ssq += x * x;
      ps[e] += x;
    }
  }
  const int fb = h ? 20 : 0, fe = h ? 39 : 20;
  for (int f = fb; f < fe; ++f)
    lin += emb1[(size_t)f * V_VOC + si[r][f]] * sx[r][f];

  float s2 = 0.f;
#pragma unroll
  for (int e = 0; e < 16; ++e) {
    float t = ps[e] + __shfl_xor(ps[e], 1);
    s2 += t * t;
  }
  // s2 is pair-total (identical on both lanes); lin/ssq are per-half partials.
  float tot = lin + 0.5f * (0.5f * s2 - ssq);
  tot += __shfl_xor(tot, 1);
  if (h == 0) out[b] = tot + consts[0];
}

// ---------------- host launch ----------------------------------------------------------------
extern "C" void kernel_launch(void* const* d_in, const int* in_sizes, int n_in,
                              void* d_out, int out_size, void* d_ws, size_t ws_size,
                              hipStream_t stream) {
  const int*   Xi   = (const int*)d_in[0];
  const float* Xv   = (const float*)d_in[1];
  const float* emb1 = (const float*)d_in[2];
  const float* emb2 = (const float*)d_in[3];
  const float* W1   = (const float*)d_in[4];
  const float* g1   = (const float*)d_in[6];
  const float* W2   = (const float*)d_in[8];
  const float* g2   = (const float*)d_in[10];
  const float* be2  = (const float*)d_in[11];
  const float* bias = (const float*)d_in[12];
  float* out = (float*)d_out;
  char* ws = (char*)d_ws;

  const size_t SZ_XT = (size_t)D_PAD * B_ROWS * 2;           // 83.9 MB
  const size_t SZ_FB = (size_t)F_FEAT * B_ROWS * 4;          // 10.2 MB

  size_t off = 0;
  unsigned short* XT = (unsigned short*)(ws + off); off += SZ_XT;
  float* M   = (float*)(ws + off); off += (size_t)D_PAD * D_PAD * 4;
  float* A1  = (float*)(ws + off); off += 512 * 4;
  float* A2  = (float*)(ws + off); off += 256 * 4;
  float* G   = (float*)(ws + off); off += (size_t)624 * 256 * 4;
  float* GW  = (float*)(ws + off); off += D_PAD * 4;
  float* CN  = (float*)(ws + off); off += 256;
  int*   XIT = (int*)(ws + off);   off += SZ_FB;
  float* XVT = (float*)(ws + off); off += SZ_FB;
  // total ~107 MB

  k0_prep<<<512, 256, 0, stream>>>(Xi, Xv, XIT, XVT, M, XT);
  k1f_gather<<<256, 1024, 0, stream>>>(XIT, XVT, emb2, XT);
  k2_syrk<<<15 * KSPLIT, 256, 0, stream>>>(XT, M);
  k_mirror<<<D_PAD, 256, 0, stream>>>(M);
  qform<<<256, 256, 0, stream>>>(M, W1, 512, g1, A1);
  k3c_G<<<624, 256, 0, stream>>>(W1, A1, W2, G);
  qform<<<128, 256, 0, stream>>>(M, G, 256, g2, A2);
  k3e_final<<<1, 256, 0, stream>>>(G, A2, M, be2, bias, GW, CN);
  k5_out<<<512, 256, 0, stream>>>(Xi, Xv, emb1, XT, GW, CN, out);
}